// Round 5
// baseline (94.398 us; speedup 1.0000x reference)
//
#include <hip/hip_runtime.h>

typedef unsigned long long u64;

#define NIMG 4
#define H 256
#define W 256
#define NPIX (H*W)           // 65536 per image
#define NTOT (NIMG*NPIX)     // 262144
#define WPR 4                // u64 words per row (256 bits)
#define WPI (H*WPR)          // 1024 words per image
#define WPB (NIMG*WPI)       // 4096 words per branch
#define XT 16                // columns per edt tile block
#define NSKEL 8              // skeleton blocks (1 per branch-image)
#define NEDT 128             // edt tile blocks (also run the final phase)
#define NB2 (NSKEL+NEDT)     // 136 blocks: all co-resident (<=256 CUs)

// ---------------------------------------------------------------------------
// Bit-parallel morphology helpers. Bit b of word k = pixel x = 64k+b.
// Erode = AND over cross; OOB=1.  Dilate = OR over 3x3 box; OOB=0.
// ---------------------------------------------------------------------------
__device__ __forceinline__ void erode_from(const u64 S[][WPR], int y, u64 out[WPR]) {
  u64 c[WPR], up[WPR], dn[WPR];
#pragma unroll
  for (int k = 0; k < WPR; ++k) {
    c[k]  = S[y][k];
    up[k] = (y > 0)     ? S[y-1][k] : ~0ULL;
    dn[k] = (y < H-1)   ? S[y+1][k] : ~0ULL;
  }
#pragma unroll
  for (int k = 0; k < WPR; ++k) {
    u64 l = (c[k] << 1) | ((k > 0)     ? (c[k-1] >> 63) : 1ULL);
    u64 r = (c[k] >> 1) | ((k < WPR-1) ? (c[k+1] << 63) : 0x8000000000000000ULL);
    out[k] = c[k] & up[k] & dn[k] & l & r;
  }
}

__device__ __forceinline__ void dilate_from(const u64 S[][WPR], int y, u64 out[WPR]) {
  u64 v[WPR];
#pragma unroll
  for (int k = 0; k < WPR; ++k) {
    u64 a = S[y][k];
    if (y > 0)   a |= S[y-1][k];
    if (y < H-1) a |= S[y+1][k];
    v[k] = a;
  }
#pragma unroll
  for (int k = 0; k < WPR; ++k) {
    u64 l = (v[k] << 1) | ((k > 0)     ? (v[k-1] >> 63) : 0ULL);
    u64 r = (v[k] >> 1) | ((k < WPR-1) ? (v[k+1] << 63) : 0ULL);
    out[k] = v[k] | l | r;
  }
}

// ---------------------------------------------------------------------------
// K1: prep — round-0 proven form (1 px/thread, NO loop). Packs yt and
// (pp>0.5) bitmasks only; pp itself is RECOMPUTED in the final phase
// (round-2 proven, identical float expression => identical bits), so the
// 1 MB pp buffer is gone. Block 0 inits rmm identities + sums + counters —
// a kernel boundary ahead of any use (kills the barrier-init race).
// ---------------------------------------------------------------------------
__global__ void __launch_bounds__(256) prep_kernel(
    const float* __restrict__ y_pred, const int* __restrict__ y_true,
    u64* __restrict__ mask_bits, unsigned* __restrict__ rmm_u,
    double* __restrict__ sums, unsigned* __restrict__ cnts) {
  if (blockIdx.x == 0) {
    if (threadIdx.x < 16) rmm_u[threadIdx.x] = (threadIdx.x & 1) ? 0x7F800000u : 0u; // min:+inf, max:0
    else if (threadIdx.x < 20) sums[threadIdx.x - 16] = 0.0;
    else if (threadIdx.x < 30) cnts[threadIdx.x - 20] = 0u;  // 8 skel flags + done + barrier
  }
  int i = blockIdx.x * 256 + threadIdx.x;
  float x = y_pred[i];
  float p = 1.0f / (1.0f + expf(-x));
  float q = 1.0f / (1.0f + expf(-(2.0f * p - 1.0f)));
  u64 bt = __ballot(y_true[i] > 0);
  u64 bp = __ballot(q > 0.5f);
  if ((threadIdx.x & 63) == 0) {
    mask_bits[i >> 6] = bt;          // branch 0: true mask
    mask_bits[WPB + (i >> 6)] = bp;  // branch 1: pred hard mask (pp>0.5)
  }
}

// ---------------------------------------------------------------------------
// K2: morpho+final fused — 136 blocks, plain launch.
//  blocks 0..7   (skel): 10-iter bit-packed soft_skel -> skel_bits; ONE
//                 release fence; per-image flag (round-4 proven); arrive at
//                 the grid barrier (cnts[9]) and EXIT.
//  blocks 8..135 (edt):  EDT phase1+2 (proven), dist in regs; round-4
//                 handshake (poll fast skel flag, sc1-stage skel words);
//                 fused rmax/rmin atomics; release fence; arrive at barrier;
//                 t0 spins to 136 (spread = slowest EDT block, same wait a
//                 kernel boundary would impose, minus the ~6us dispatch);
//                 acquire fence (round-3-proven buffer_inv pattern); then
//                 the round-2-proven FINAL phase: 8 px/thread q-terms with
//                 recomputed pp, 4 double atomics, last-block finalize.
// ---------------------------------------------------------------------------
__global__ void __launch_bounds__(256, 1) morpho_final_kernel(
    const float* __restrict__ y_pred, const int* __restrict__ y_true,
    const u64* __restrict__ mask_bits, u64* __restrict__ skel_bits,
    float* __restrict__ edt, unsigned* __restrict__ rmm_u,
    double* __restrict__ sums, unsigned* __restrict__ cnts,
    float* __restrict__ out) {
  __shared__ u64 SA[H][WPR];
  __shared__ u64 SB[H][WPR];
  __shared__ float col2[H][XT + 1];   // pad 17: 2-way aliasing free on gfx950
  __shared__ u64 srow[H];
  __shared__ float smax[4], smin[4];
  __shared__ float part[4][4];
  int t = threadIdx.x;

  if (blockIdx.x < NSKEL) {
    // --- soft_skel, bit-packed, 1 thread per row, ONE barrier per level ---
    int bi = blockIdx.x;
    int y = t;
    int base = bi * WPI;
    u64 a[WPR], cur[WPR], e[WPR], d[WPR], sk[WPR];
#pragma unroll
    for (int k = 0; k < WPR; ++k) { a[k] = mask_bits[base + y*WPR + k]; SA[y][k] = a[k]; }
    __syncthreads();
    erode_from(SA, y, e);                 // E1 = erode(a)
#pragma unroll
    for (int k = 0; k < WPR; ++k) SB[y][k] = e[k];
    __syncthreads();                      // SB visible; all SA reads complete
    dilate_from(SB, y, d);                // open(a)
#pragma unroll
    for (int k = 0; k < WPR; ++k) { sk[k] = a[k] & ~d[k]; cur[k] = e[k]; }
    u64 (*P)[WPR] = SB;                   // current erosion level E_k
    u64 (*Q)[WPR] = SA;                   // dead buffer
    for (int it = 0; it < 10; ++it) {     // levels 1..10
      erode_from(P, y, e);                // E_{k+1}
#pragma unroll
      for (int k = 0; k < WPR; ++k) Q[y][k] = e[k];   // overwrite dead data
      __syncthreads();                    // publish Q; P reads all done
      dilate_from(Q, y, d);               // open(E_k)
#pragma unroll
      for (int k = 0; k < WPR; ++k) { sk[k] |= cur[k] & ~d[k]; cur[k] = e[k]; }
      u64 (*T)[WPR] = P; P = Q; Q = T;
    }
#pragma unroll
    for (int k = 0; k < WPR; ++k) skel_bits[base + y*WPR + k] = sk[k];
    __syncthreads();                      // all stores issued + vmcnt drained
    if (t == 0) {
      __threadfence();                    // release: writeback this XCD's L2
      atomicAdd(&cnts[bi], 1u);           // per-image flag (round-4 handshake)
      atomicAdd(&cnts[9], 1u);            // arrive at grid barrier
    }
    return;                               // skel blocks don't run final phase
  }

  // ===================== EDT blocks (8..135) =====================
  {
    int bt = blockIdx.x - NSKEL;
    int bi = bt >> 4;                    // 0..7 = branch*4+img
    int xt = bt & 15;
    int x0 = xt * XT;
    int kx = x0 >> 6;                    // all tile columns in this u64 word
    int sh0 = x0 & 63;
    // phase 1: thread = row y; horizontal EDT g via clz/ctz -> col2 = g^2
    {
      int y = t;
      const u64* row = mask_bits + bi*WPI + y*WPR;
      u64 z[WPR];
#pragma unroll
      for (int k = 0; k < WPR; ++k) z[k] = ~row[k];   // background bits
#pragma unroll
      for (int xx = 0; xx < XT; ++xx) {
        int x = x0 + xx;
        int bx = x & 63;
        int ld = 512;
        {
          u64 w = z[kx] & ((bx == 63) ? ~0ULL : ((1ULL << (bx+1)) - 1ULL));
          for (int k = kx; ; ) {
            if (w) { int pos = 63 - __builtin_clzll(w) + (k << 6); ld = x - pos; break; }
            if (--k < 0) break;
            w = z[k];
          }
        }
        int rd = 512;
        {
          u64 w = z[kx] & (~0ULL << bx);
          for (int k = kx; ; ) {
            if (w) { int pos = __builtin_ctzll(w) + (k << 6); rd = pos - x; break; }
            if (++k > WPR-1) break;
            w = z[k];
          }
        }
        int g = min(ld, rd);
        col2[y][xx] = (float)(g * g);
      }
    }
    __syncthreads();
    // phase 2: thread = (x, ygrp); early-exit envelope; dist kept in regs
    int x  = t & (XT - 1);
    int yg = t >> 4;
    float dist_r[16];
#pragma unroll
    for (int j = 0; j < 16; ++j) {
      int y = yg * 16 + j;
      float best = col2[y][x];
      for (int k = 1; k < H; ++k) {
        float k2 = (float)(k * k);
        if (k2 >= best) break;           // no farther candidate can improve
        int ym = y - k, yq = y + k;
        if (ym >= 0) best = fminf(best, col2[ym][x] + k2);
        if (yq < H)  best = fminf(best, col2[yq][x] + k2);
      }
      float dist = sqrtf(best);
      dist_r[j] = dist;
      edt[bi*NPIX + y*W + x0 + x] = dist;
    }
    // --- round-4 handshake: wait for this image's skel flag (fast side) ---
    if (t == 0) {
      while (__hip_atomic_load(&cnts[bi], __ATOMIC_RELAXED,
                               __HIP_MEMORY_SCOPE_AGENT) == 0u)
        __builtin_amdgcn_s_sleep(2);
    }
    __syncthreads();
    // stage skel words: 1 sc1 load/thread (bypasses stale L2 -> LLC)
    srow[t] = __hip_atomic_load(&skel_bits[bi*WPI + t*WPR + kx],
                                __ATOMIC_RELAXED, __HIP_MEMORY_SCOPE_AGENT);
    __syncthreads();
    // --- fused rmax/rmin (round-4 proven tail) ---
    float vmax = 0.0f, vmin = 3.0e38f;
#pragma unroll
    for (int j = 0; j < 16; ++j) {
      int y = yg * 16 + j;
      u64 sw = srow[y];
      int sb = (int)((sw >> (sh0 + x)) & 1ULL);
      float srad = sb ? dist_r[j] : 0.0f; // == skel_radius for both branches
      vmax = fmaxf(vmax, srad);
      vmin = fminf(vmin, srad);
    }
    for (int o = 32; o > 0; o >>= 1) {
      vmax = fmaxf(vmax, __shfl_down(vmax, o, 64));
      vmin = fminf(vmin, __shfl_down(vmin, o, 64));
    }
    int wave = t >> 6, lane = t & 63;
    if (lane == 0) { smax[wave] = vmax; smin[wave] = vmin; }
    __syncthreads();
    if (t == 0) {
      float mx = smax[0], mn = smin[0];
      for (int wv = 1; wv < 4; ++wv) { mx = fmaxf(mx, smax[wv]); mn = fminf(mn, smin[wv]); }
      atomicMax(&rmm_u[bi*2 + 0], __float_as_uint(mx));
      atomicMin(&rmm_u[bi*2 + 1], __float_as_uint(mn));
      // --- arrive at grid barrier + spin to full count (136) ---
      __threadfence();                   // release: edt writes -> LLC
      atomicAdd(&cnts[9], 1u);
      while (__hip_atomic_load(&cnts[9], __ATOMIC_RELAXED,
                               __HIP_MEMORY_SCOPE_AGENT) < NB2)
        __builtin_amdgcn_s_sleep(2);
    }
    __syncthreads();
    __threadfence();                     // acquire: invalidate stale L1/L2
  }

  // ===================== FINAL phase (128 blocks, 8 px/thread) =====================
  {
    int fb = blockIdx.x - NSKEL;           // 0..127
    int i0 = (fb * 256 + t) * 8;           // 8 px/thread, same u64 word
    int img = i0 >> 16;
    int wi  = i0 >> 6;
    int b0  = i0 & 63;                     // b0 <= 56: 8 bits in same word
    u64 mw_t = mask_bits[wi];
    u64 sw_t = skel_bits[wi];
    u64 sw_p = skel_bits[WPB + wi];
    float4 xp0 = *(const float4*)(y_pred + i0);
    float4 xp1 = *(const float4*)(y_pred + i0 + 4);
    float4 dt0 = *(const float4*)(edt + i0);
    float4 dt1 = *(const float4*)(edt + i0 + 4);
    float4 dp0 = *(const float4*)(edt + NTOT + i0);
    float4 dp1 = *(const float4*)(edt + NTOT + i0 + 4);
    float rmax_t = fmaxf(__uint_as_float(rmm_u[img*2 + 0]), 1.0f);
    float rmin_t = fmaxf(__uint_as_float(rmm_u[img*2 + 1]), 1.0f);
    float rmax_p = fmaxf(__uint_as_float(rmm_u[(4+img)*2 + 0]), 1.0f);
    float rmin_p = fmaxf(__uint_as_float(rmm_u[(4+img)*2 + 1]), 1.0f);
    float xs[8] = {xp0.x,xp0.y,xp0.z,xp0.w,xp1.x,xp1.y,xp1.z,xp1.w};
    float dts[8] = {dt0.x,dt0.y,dt0.z,dt0.w,dt1.x,dt1.y,dt1.z,dt1.w};
    float dps[8] = {dp0.x,dp0.y,dp0.z,dp0.w,dp1.x,dp1.y,dp1.z,dp1.w};
    float q1 = 0.f, q2 = 0.f, q3 = 0.f, q4 = 0.f;
#pragma unroll
    for (int j = 0; j < 8; ++j) {
      int b = b0 + j;
      // pp recomputed — identical float expression everywhere (round-2 proven)
      float p = 1.0f / (1.0f + expf(-xs[j]));
      float ppv = 1.0f / (1.0f + expf(-(2.0f * p - 1.0f)));
      // --- true branch (binary) ---
      int m_t = (int)((mw_t >> b) & 1ULL);
      int s_t = (int)((sw_t >> b) & 1ULL);
      float distances_t = m_t ? dts[j] : 0.0f;
      float skelrad_t   = s_t ? distances_t : 0.0f;
      float dmn_t = fminf(distances_t, rmax_t) / rmax_t;
      float srn_t = skelrad_t / rmax_t;
      float In_t  = s_t ? (rmax_t - skelrad_t + rmin_t) / rmax_t : 0.0f;
      float q_vl   = m_t ? dmn_t : 0.0f;
      float q_slvl = m_t ? srn_t : 0.0f;
      float q_sl   = s_t ? In_t  : 0.0f;
      // --- pred branch (probabilistic) ---
      int s_pb = (int)((sw_p >> b) & 1ULL);
      float skel_in_p = s_pb ? ppv : 0.0f;      // skel_pred_prob
      bool msk_p = ppv > 0.5f;
      bool sk_p  = skel_in_p > 0.5f;
      float distances_p = msk_p ? dps[j] : 0.0f;
      float skelrad_p   = sk_p ? distances_p : 0.0f;
      float dmn_p = fminf(distances_p, rmax_p) / rmax_p;
      float srn_p = skelrad_p / rmax_p;
      float In_p  = sk_p ? (rmax_p - skelrad_p + rmin_p) / rmax_p : 0.0f;
      float q_vp   = dmn_p * ppv;
      float q_spvp = srn_p * ppv;
      float q_sp   = In_p * skel_in_p;
      q1 += q_sp * q_vl;
      q2 += (q_spvp != 0.0f && q_slvl == 0.0f) ? q_spvp * q_sp : q_slvl * q_sp;
      q3 += q_sl * q_vp;
      q4 += (q_slvl != 0.0f && q_spvp == 0.0f) ? q_slvl * q_sl : q_spvp * q_sl;
    }
    for (int o = 32; o > 0; o >>= 1) {
      q1 += __shfl_down(q1, o, 64);
      q2 += __shfl_down(q2, o, 64);
      q3 += __shfl_down(q3, o, 64);
      q4 += __shfl_down(q4, o, 64);
    }
    int wave = t >> 6, lane = t & 63;
    if (lane == 0) { part[wave][0]=q1; part[wave][1]=q2; part[wave][2]=q3; part[wave][3]=q4; }
    __syncthreads();
    if (t == 0) {
      float a0=0,a1=0,a2=0,a3=0;
      for (int wv = 0; wv < 4; ++wv) {
        a0 += part[wv][0]; a1 += part[wv][1]; a2 += part[wv][2]; a3 += part[wv][3];
      }
      atomicAdd(&sums[0], (double)a0);
      atomicAdd(&sums[1], (double)a1);
      atomicAdd(&sums[2], (double)a2);
      atomicAdd(&sums[3], (double)a3);
      __threadfence();                    // publish sums before counting done
      unsigned c = atomicAdd(&cnts[8], 1u);
      if (c == NEDT - 1) {                // last block finalizes (device-scope
        double s0 = atomicAdd(&sums[0], 0.0);   // atomic loads for coherence)
        double s1 = atomicAdd(&sums[1], 0.0);
        double s2 = atomicAdd(&sums[2], 0.0);
        double s3 = atomicAdd(&sums[3], 0.0);
        double wp  = (s0 + 1.0) / (s1 + 1.0);
        double wsn = (s2 + 1.0) / (s3 + 1.0);
        out[0] = (float)(1.0 - 2.0 * (wp * wsn) / (wp + wsn));
      }
    }
  }
}

extern "C" void kernel_launch(void* const* d_in, const int* in_sizes, int n_in,
                              void* d_out, int out_size, void* d_ws, size_t ws_size,
                              hipStream_t stream) {
  (void)in_sizes; (void)n_in; (void)out_size; (void)ws_size;
  const float* y_pred = (const float*)d_in[0];
  const int*   y_true = (const int*)d_in[1];
  float* out = (float*)d_out;
  char* ws = (char*)d_ws;

  // workspace layout (bytes) — pp buffer eliminated (recomputed in final phase)
  float* edt       = (float*)(ws + 0);          // 524288 f (2,097,152 B) [branch][img][y][x]
  u64*   mask_bits = (u64*)  (ws + 2097152);    // 8192 u64 (65,536 B)
  u64*   skel_bits = (u64*)  (ws + 2162688);    // 8192 u64 (65,536 B)
  unsigned* rmm_u  = (unsigned*)(ws + 2228224); // 16 u32
  double* sums     = (double*)(ws + 2228288);   // 4 d
  unsigned* cnts   = (unsigned*)(ws + 2228320); // [0..7] skel flags, [8] done, [9] barrier

  prep_kernel<<<NTOT/256, 256, 0, stream>>>(y_pred, y_true, mask_bits, rmm_u, sums, cnts);
  morpho_final_kernel<<<NB2, 256, 0, stream>>>(y_pred, y_true, mask_bits, skel_bits,
                                               edt, rmm_u, sums, cnts, out);
}

// Round 6
// 90.990 us; speedup vs baseline: 1.0375x; 1.0375x over previous
//
#include <hip/hip_runtime.h>

typedef unsigned long long u64;

#define NIMG 4
#define H 256
#define W 256
#define NPIX (H*W)           // 65536 per image
#define NTOT (NIMG*NPIX)     // 262144
#define WPR 4                // u64 words per row (256 bits)
#define WPI (H*WPR)          // 1024 words per image
#define WPB (NIMG*WPI)       // 4096 words per branch
#define XT 8                 // columns per tile block (both branches)
#define NSKEL 8              // skeleton blocks (1 per branch-image)
#define NTILE 128            // tile blocks: 4 img x 32 col-tiles
#define NB2 (NSKEL+NTILE)    // 136 blocks: all co-resident (<=256 CUs)

// ---------------------------------------------------------------------------
// Bit-parallel morphology helpers. Bit b of word k = pixel x = 64k+b.
// Erode = AND over cross; OOB=1.  Dilate = OR over 3x3 box; OOB=0.
// ---------------------------------------------------------------------------
__device__ __forceinline__ void erode_from(const u64 S[][WPR], int y, u64 out[WPR]) {
  u64 c[WPR], up[WPR], dn[WPR];
#pragma unroll
  for (int k = 0; k < WPR; ++k) {
    c[k]  = S[y][k];
    up[k] = (y > 0)     ? S[y-1][k] : ~0ULL;
    dn[k] = (y < H-1)   ? S[y+1][k] : ~0ULL;
  }
#pragma unroll
  for (int k = 0; k < WPR; ++k) {
    u64 l = (c[k] << 1) | ((k > 0)     ? (c[k-1] >> 63) : 1ULL);
    u64 r = (c[k] >> 1) | ((k < WPR-1) ? (c[k+1] << 63) : 0x8000000000000000ULL);
    out[k] = c[k] & up[k] & dn[k] & l & r;
  }
}

__device__ __forceinline__ void dilate_from(const u64 S[][WPR], int y, u64 out[WPR]) {
  u64 v[WPR];
#pragma unroll
  for (int k = 0; k < WPR; ++k) {
    u64 a = S[y][k];
    if (y > 0)   a |= S[y-1][k];
    if (y < H-1) a |= S[y+1][k];
    v[k] = a;
  }
#pragma unroll
  for (int k = 0; k < WPR; ++k) {
    u64 l = (v[k] << 1) | ((k > 0)     ? (v[k-1] >> 63) : 0ULL);
    u64 r = (v[k] >> 1) | ((k < WPR-1) ? (v[k+1] << 63) : 0ULL);
    out[k] = v[k] | l | r;
  }
}

// ---------------------------------------------------------------------------
// K1: prep — round-0 proven form (1 px/thread, NO loop). Packs the true mask
// and the pred hard mask (pp>0.5, identical float expression everywhere =>
// identical bits). Block 0 inits rmm identities + sums + all counters a full
// kernel boundary before any use.
// ---------------------------------------------------------------------------
__global__ void __launch_bounds__(256) prep_kernel(
    const float* __restrict__ y_pred, const int* __restrict__ y_true,
    u64* __restrict__ mask_bits, unsigned* __restrict__ rmm_u,
    double* __restrict__ sums, unsigned* __restrict__ cnts) {
  if (blockIdx.x == 0) {
    if (threadIdx.x < 16) rmm_u[threadIdx.x] = (threadIdx.x & 1) ? 0x7F800000u : 0u; // min:+inf, max:0
    else if (threadIdx.x < 20) sums[threadIdx.x - 16] = 0.0;
    else if (threadIdx.x < 34) cnts[threadIdx.x - 20] = 0u;  // [0..7] skel flags, [8] done, [10..13] img barriers
  }
  int i = blockIdx.x * 256 + threadIdx.x;
  float x = y_pred[i];
  float p = 1.0f / (1.0f + expf(-x));
  float q = 1.0f / (1.0f + expf(-(2.0f * p - 1.0f)));
  u64 bt = __ballot(y_true[i] > 0);
  u64 bp = __ballot(q > 0.5f);
  if ((threadIdx.x & 63) == 0) {
    mask_bits[i >> 6] = bt;          // branch 0: true mask
    mask_bits[WPB + (i >> 6)] = bp;  // branch 1: pred hard mask (pp>0.5)
  }
}

// EDT pass for one branch of the tile: phase 1 (horizontal, clz/ctz) into
// col2, phase 2 (vertical early-exit envelope) into DIST[8] registers.
// SAVE_MASK: stash this row's mask word for the q-phase.
#define EDT_PASS(MROW, DIST, SAVE_MASK)                                        \
  {                                                                            \
    int y = t;                                                                 \
    const u64* row = (MROW) + y*WPR;                                           \
    u64 z[WPR];                                                                \
    _Pragma("unroll")                                                          \
    for (int k = 0; k < WPR; ++k) z[k] = ~row[k];   /* background bits */      \
    if (SAVE_MASK) msk_row[y] = row[kx];                                       \
    _Pragma("unroll")                                                          \
    for (int xx = 0; xx < XT; ++xx) {                                          \
      int x = x0 + xx;                                                         \
      int bx = x & 63;                                                         \
      int ld = 512;                                                            \
      {                                                                        \
        u64 w = z[kx] & ((bx == 63) ? ~0ULL : ((1ULL << (bx+1)) - 1ULL));      \
        for (int k = kx; ; ) {                                                 \
          if (w) { int pos = 63 - __builtin_clzll(w) + (k << 6); ld = x - pos; break; } \
          if (--k < 0) break;                                                  \
          w = z[k];                                                            \
        }                                                                      \
      }                                                                        \
      int rd = 512;                                                            \
      {                                                                        \
        u64 w = z[kx] & (~0ULL << bx);                                         \
        for (int k = kx; ; ) {                                                 \
          if (w) { int pos = __builtin_ctzll(w) + (k << 6); rd = pos - x; break; } \
          if (++k > WPR-1) break;                                              \
          w = z[k];                                                            \
        }                                                                      \
      }                                                                        \
      int g = min(ld, rd);                                                     \
      col2[y][xx] = (float)(g * g);                                            \
    }                                                                          \
  }                                                                            \
  __syncthreads();                                                             \
  _Pragma("unroll")                                                            \
  for (int j = 0; j < 8; ++j) {                                                \
    int y = yg * 8 + j;                                                        \
    float best = col2[y][xq];                                                  \
    for (int k = 1; k < H; ++k) {                                              \
      float k2 = (float)(k * k);                                               \
      if (k2 >= best) break;           /* no farther candidate improves */     \
      int ym = y - k, yd = y + k;                                              \
      if (ym >= 0) best = fminf(best, col2[ym][xq] + k2);                      \
      if (yd < H)  best = fminf(best, col2[yd][xq] + k2);                      \
    }                                                                          \
    (DIST)[j] = sqrtf(best);                                                   \
  }                                                                            \
  __syncthreads();

// ---------------------------------------------------------------------------
// K2: fully fused morpho+rmm+final. 136 blocks x 256 threads, plain launch.
//  blocks 0..7   (skel): 10-iter bit-packed soft_skel -> skel_bits; ONE
//                 release fence + per-image flag (round-4 proven); exit.
//  blocks 8..135 (tile): tb -> (img, 8-column tile). Runs EDT for BOTH
//                 branches of the same tile => dist_t/dist_p for every owned
//                 pixel live in REGISTERS. No edt global buffer, no grid
//                 barrier (round-5's 62us lesson: 128 threadfence releases +
//                 full-grid spin + L2 invalidates >> kernel boundary).
//                 Cross-block traffic is scalars only:
//                  - skel bits: round-4 flag + sc1 staging (proven);
//                  - rmax/rmin: device-scope atomics (coherent at LLC) +
//                    per-image 32-block counter (release RMW, no wbl2 dirt:
//                    nothing dirty to flush) + 4 sc1 readbacks.
//                 Then the q-phase sums its own 2048 pixels from regs/LDS
//                 (ppv recomputed — round-2 proven), 4 double atomics,
//                 last-of-128 finalizes (proven tail).
// ---------------------------------------------------------------------------
__global__ void __launch_bounds__(256, 1) fused_kernel(
    const float* __restrict__ y_pred, const u64* __restrict__ mask_bits,
    u64* __restrict__ skel_bits, unsigned* __restrict__ rmm_u,
    double* __restrict__ sums, unsigned* __restrict__ cnts,
    float* __restrict__ out) {
  __shared__ u64 SA[H][WPR];
  __shared__ u64 SB[H][WPR];
  __shared__ float col2[H][XT + 1];
  __shared__ u64 srow_t[H];
  __shared__ u64 srow_p[H];
  __shared__ u64 msk_row[H];
  __shared__ float redf[4][4];
  __shared__ unsigned smm[4];
  int t = threadIdx.x;

  if (blockIdx.x < NSKEL) {
    // --- soft_skel, bit-packed, 1 thread per row, ONE barrier per level ---
    int bi = blockIdx.x;                  // branch*4+img
    int y = t;
    int base = bi * WPI;
    u64 a[WPR], cur[WPR], e[WPR], d[WPR], sk[WPR];
#pragma unroll
    for (int k = 0; k < WPR; ++k) { a[k] = mask_bits[base + y*WPR + k]; SA[y][k] = a[k]; }
    __syncthreads();
    erode_from(SA, y, e);                 // E1 = erode(a)
#pragma unroll
    for (int k = 0; k < WPR; ++k) SB[y][k] = e[k];
    __syncthreads();                      // SB visible; all SA reads complete
    dilate_from(SB, y, d);                // open(a)
#pragma unroll
    for (int k = 0; k < WPR; ++k) { sk[k] = a[k] & ~d[k]; cur[k] = e[k]; }
    u64 (*P)[WPR] = SB;                   // current erosion level E_k
    u64 (*Q)[WPR] = SA;                   // dead buffer
    for (int it = 0; it < 10; ++it) {     // levels 1..10
      erode_from(P, y, e);                // E_{k+1}
#pragma unroll
      for (int k = 0; k < WPR; ++k) Q[y][k] = e[k];   // overwrite dead data
      __syncthreads();                    // publish Q; P reads all done
      dilate_from(Q, y, d);               // open(E_k)
#pragma unroll
      for (int k = 0; k < WPR; ++k) { sk[k] |= cur[k] & ~d[k]; cur[k] = e[k]; }
      u64 (*T)[WPR] = P; P = Q; Q = T;
    }
#pragma unroll
    for (int k = 0; k < WPR; ++k) skel_bits[base + y*WPR + k] = sk[k];
    __syncthreads();                      // all stores issued + vmcnt drained
    if (t == 0) {
      __threadfence();                    // release: writeback this XCD's L2 (8 total)
      atomicAdd(&cnts[bi], 1u);           // per-(branch,image) flag
    }
    return;
  }

  // ===================== tile blocks (8..135) =====================
  int tb  = blockIdx.x - NSKEL;          // 0..127
  int img = tb >> 5;                     // 0..3
  int xt  = tb & 31;                     // 0..31
  int x0  = xt * XT;
  int kx  = x0 >> 6;                     // tile's 8 columns share this word
  int sh0 = x0 & 63;                     // <= 56
  int xq  = t & (XT - 1);                // phase-2/q column 0..7
  int yg  = t >> 3;                      // phase-2/q row group 0..31

  float dist_t[8], dist_p[8];
  EDT_PASS(mask_bits + img*WPI,       dist_t, 1)   // true branch (saves mask word)
  EDT_PASS(mask_bits + (4+img)*WPI,   dist_p, 0)   // pred branch

  // --- round-4 handshake: wait for BOTH skel flags (fast side, ~0 spin) ---
  if (t == 0) {
    while (__hip_atomic_load(&cnts[img], __ATOMIC_RELAXED,
                             __HIP_MEMORY_SCOPE_AGENT) == 0u)
      __builtin_amdgcn_s_sleep(2);
    while (__hip_atomic_load(&cnts[4+img], __ATOMIC_RELAXED,
                             __HIP_MEMORY_SCOPE_AGENT) == 0u)
      __builtin_amdgcn_s_sleep(2);
  }
  __syncthreads();
  // stage skel words for this tile (sc1: bypass stale L2, LLC-coherent)
  srow_t[t] = __hip_atomic_load(&skel_bits[img*WPI + t*WPR + kx],
                                __ATOMIC_RELAXED, __HIP_MEMORY_SCOPE_AGENT);
  srow_p[t] = __hip_atomic_load(&skel_bits[(4+img)*WPI + t*WPR + kx],
                                __ATOMIC_RELAXED, __HIP_MEMORY_SCOPE_AGENT);
  __syncthreads();

  // --- fused rmax/rmin for BOTH branches (regs + LDS only) ---
  float vmax_t = 0.0f, vmin_t = 3.0e38f, vmax_p = 0.0f, vmin_p = 3.0e38f;
#pragma unroll
  for (int j = 0; j < 8; ++j) {
    int y = yg * 8 + j;
    int sb_t = (int)((srow_t[y] >> (sh0 + xq)) & 1ULL);
    int sb_p = (int)((srow_p[y] >> (sh0 + xq)) & 1ULL);
    float srt = sb_t ? dist_t[j] : 0.0f;  // skel_radius, true branch
    float srp = sb_p ? dist_p[j] : 0.0f;  // skel_radius, pred branch
    vmax_t = fmaxf(vmax_t, srt); vmin_t = fminf(vmin_t, srt);
    vmax_p = fmaxf(vmax_p, srp); vmin_p = fminf(vmin_p, srp);
  }
  for (int o = 32; o > 0; o >>= 1) {
    vmax_t = fmaxf(vmax_t, __shfl_down(vmax_t, o, 64));
    vmin_t = fminf(vmin_t, __shfl_down(vmin_t, o, 64));
    vmax_p = fmaxf(vmax_p, __shfl_down(vmax_p, o, 64));
    vmin_p = fminf(vmin_p, __shfl_down(vmin_p, o, 64));
  }
  int wave = t >> 6, lane = t & 63;
  if (lane == 0) { redf[wave][0]=vmax_t; redf[wave][1]=vmin_t;
                   redf[wave][2]=vmax_p; redf[wave][3]=vmin_p; }
  __syncthreads();
  if (t == 0) {
    float mxt=redf[0][0], mnt=redf[0][1], mxp=redf[0][2], mnp=redf[0][3];
    for (int wv = 1; wv < 4; ++wv) {
      mxt = fmaxf(mxt, redf[wv][0]); mnt = fminf(mnt, redf[wv][1]);
      mxp = fmaxf(mxp, redf[wv][2]); mnp = fminf(mnp, redf[wv][3]);
    }
    atomicMax(&rmm_u[img*2 + 0], __float_as_uint(mxt));
    atomicMin(&rmm_u[img*2 + 1], __float_as_uint(mnt));
    atomicMax(&rmm_u[(4+img)*2 + 0], __float_as_uint(mxp));
    atomicMin(&rmm_u[(4+img)*2 + 1], __float_as_uint(mnp));
    // per-image sub-barrier: release RMW orders the atomics above (all at
    // LLC already — nothing dirty in L2, unlike round-5's disaster)
    __hip_atomic_fetch_add(&cnts[10+img], 1u, __ATOMIC_RELEASE,
                           __HIP_MEMORY_SCOPE_AGENT);
    while (__hip_atomic_load(&cnts[10+img], __ATOMIC_RELAXED,
                             __HIP_MEMORY_SCOPE_AGENT) < 32u)
      __builtin_amdgcn_s_sleep(2);
  }
  __syncthreads();
  if (t < 4) {
    int idx = (t < 2) ? (img*2 + t) : ((4+img)*2 + (t-2));
    smm[t] = __hip_atomic_load(&rmm_u[idx], __ATOMIC_RELAXED,
                               __HIP_MEMORY_SCOPE_AGENT);
  }
  __syncthreads();
  float rmax_t = fmaxf(__uint_as_float(smm[0]), 1.0f);
  float rmin_t = fmaxf(__uint_as_float(smm[1]), 1.0f);
  float rmax_p = fmaxf(__uint_as_float(smm[2]), 1.0f);
  float rmin_p = fmaxf(__uint_as_float(smm[3]), 1.0f);

  // --- q-phase over this block's OWN 2048 pixels (dist in regs) ---
  float q1 = 0.f, q2 = 0.f, q3 = 0.f, q4 = 0.f;
#pragma unroll
  for (int j = 0; j < 8; ++j) {
    int y = yg * 8 + j;
    float xv = y_pred[img*NPIX + y*W + x0 + xq];
    float p = 1.0f / (1.0f + expf(-xv));
    float ppv = 1.0f / (1.0f + expf(-(2.0f * p - 1.0f)));  // round-2 proven exact
    int b = sh0 + xq;
    int m_t  = (int)((msk_row[y] >> b) & 1ULL);
    int s_t  = (int)((srow_t[y] >> b) & 1ULL);
    int s_pb = (int)((srow_p[y] >> b) & 1ULL);
    // --- true branch (binary) ---
    float distances_t = m_t ? dist_t[j] : 0.0f;
    float skelrad_t   = s_t ? distances_t : 0.0f;
    float dmn_t = fminf(distances_t, rmax_t) / rmax_t;
    float srn_t = skelrad_t / rmax_t;
    float In_t  = s_t ? (rmax_t - skelrad_t + rmin_t) / rmax_t : 0.0f;
    float q_vl   = m_t ? dmn_t : 0.0f;
    float q_slvl = m_t ? srn_t : 0.0f;
    float q_sl   = s_t ? In_t  : 0.0f;
    // --- pred branch (probabilistic) ---
    float skel_in_p = s_pb ? ppv : 0.0f;      // skel_pred_prob
    bool msk_p = ppv > 0.5f;
    bool sk_p  = skel_in_p > 0.5f;
    float distances_p = msk_p ? dist_p[j] : 0.0f;
    float skelrad_p   = sk_p ? distances_p : 0.0f;
    float dmn_p = fminf(distances_p, rmax_p) / rmax_p;
    float srn_p = skelrad_p / rmax_p;
    float In_p  = sk_p ? (rmax_p - skelrad_p + rmin_p) / rmax_p : 0.0f;
    float q_vp   = dmn_p * ppv;
    float q_spvp = srn_p * ppv;
    float q_sp   = In_p * skel_in_p;
    q1 += q_sp * q_vl;
    q2 += (q_spvp != 0.0f && q_slvl == 0.0f) ? q_spvp * q_sp : q_slvl * q_sp;
    q3 += q_sl * q_vp;
    q4 += (q_slvl != 0.0f && q_spvp == 0.0f) ? q_slvl * q_sl : q_spvp * q_sl;
  }
  for (int o = 32; o > 0; o >>= 1) {
    q1 += __shfl_down(q1, o, 64);
    q2 += __shfl_down(q2, o, 64);
    q3 += __shfl_down(q3, o, 64);
    q4 += __shfl_down(q4, o, 64);
  }
  if (lane == 0) { redf[wave][0]=q1; redf[wave][1]=q2; redf[wave][2]=q3; redf[wave][3]=q4; }
  __syncthreads();
  if (t == 0) {
    float a0=0,a1=0,a2=0,a3=0;
    for (int wv = 0; wv < 4; ++wv) {
      a0 += redf[wv][0]; a1 += redf[wv][1]; a2 += redf[wv][2]; a3 += redf[wv][3];
    }
    atomicAdd(&sums[0], (double)a0);
    atomicAdd(&sums[1], (double)a1);
    atomicAdd(&sums[2], (double)a2);
    atomicAdd(&sums[3], (double)a3);
    __threadfence();                    // publish sums before counting done
    unsigned c = atomicAdd(&cnts[8], 1u);
    if (c == NTILE - 1) {               // last block finalizes (device-scope
      double s0 = atomicAdd(&sums[0], 0.0);   // atomic loads for coherence)
      double s1 = atomicAdd(&sums[1], 0.0);
      double s2 = atomicAdd(&sums[2], 0.0);
      double s3 = atomicAdd(&sums[3], 0.0);
      double wp  = (s0 + 1.0) / (s1 + 1.0);
      double wsn = (s2 + 1.0) / (s3 + 1.0);
      out[0] = (float)(1.0 - 2.0 * (wp * wsn) / (wp + wsn));
    }
  }
}

extern "C" void kernel_launch(void* const* d_in, const int* in_sizes, int n_in,
                              void* d_out, int out_size, void* d_ws, size_t ws_size,
                              hipStream_t stream) {
  (void)in_sizes; (void)n_in; (void)out_size; (void)ws_size;
  const float* y_pred = (const float*)d_in[0];
  const int*   y_true = (const int*)d_in[1];
  float* out = (float*)d_out;
  char* ws = (char*)d_ws;

  // workspace layout (bytes) — edt and pp buffers eliminated entirely
  u64*   mask_bits = (u64*)  (ws + 0);          // 8192 u64 (65,536 B)
  u64*   skel_bits = (u64*)  (ws + 65536);      // 8192 u64 (65,536 B)
  unsigned* rmm_u  = (unsigned*)(ws + 131072);  // 16 u32
  double* sums     = (double*)(ws + 131136);    // 4 d
  unsigned* cnts   = (unsigned*)(ws + 131168);  // [0..7] skel flags, [8] done, [10..13] img barriers

  prep_kernel<<<NTOT/256, 256, 0, stream>>>(y_pred, y_true, mask_bits, rmm_u, sums, cnts);
  fused_kernel<<<NB2, 256, 0, stream>>>(y_pred, mask_bits, skel_bits, rmm_u, sums, cnts, out);
}